// Round 14
// baseline (165.359 us; speedup 1.0000x reference)
//
#include <hip/hip_runtime.h>

typedef __bf16 bf16;
typedef __bf16 bf16x4v __attribute__((ext_vector_type(4)));
typedef __bf16 bf16x8 __attribute__((ext_vector_type(8)));
typedef float f32x4 __attribute__((ext_vector_type(4)));
typedef short s16x4 __attribute__((ext_vector_type(4)));

#define MFMA_X32(A, B, C) __builtin_amdgcn_mfma_f32_16x16x32_bf16(A, B, C, 0, 0, 0)

static __device__ __forceinline__ float fast_exp2(float x) {
  float r;
  asm volatile("v_exp_f32 %0, %1\n\ts_nop 0" : "=v"(r) : "v"(x));
  return r;
}

static __device__ __forceinline__ void gll16(const void* g, void* l) {
  __builtin_amdgcn_global_load_lds(
      (const __attribute__((address_space(1))) void*)g,
      (__attribute__((address_space(3))) void*)l, 16, 0, 0);
}

// ---- workspace byte offsets (R8 layout) ----
#define WT_OFF 0              // Wt bf16 [3][256 n][256 k]          (384 KB)
#define Q_OFF 393216          // Q' bf16 [16384][256] (pre-scaled)   (8 MB)
#define K_OFF 8781824         // Kc bf16 chunk-permuted (see below)  (8 MB)
#define V_OFF 17170432        // Vc bf16 32-key-permuted             (8 MB)
// Kc: per (b, 16-key chunk) 8KB block; element (key s, dim n) at
//   (n>>5)*512 + ((n>>3)&3)*128 + (s&15)*8 + (n&7)
//   => flash K-frag ds_read_b128 addr = base + kt*1024 + lane*16 (LINEAR).
// Vc: per (b, 32-key chunk) 16KB block; element (key s, dim n) at
//   byte = (n>>4)*1024 + ((s>>2)&3)*256 + (n&15)*16 + ((s>>4)*4 + (s&3))*2
//   => flash PV B-frag (16x16x32) addr = base + dt*1024 + lane*16 (LINEAR);
//   k=quad*8+j <-> key=(j>>2)*16+quad*4+(j&3) matches the concatenated S^T
//   C-frags of two 16-key chunks as the PV A-operand (x32-rate PV).
// R14 = R13 (best measured: 154.9us total; flash R8-identical by counter
// checksum) + proj parallelism doubling: grid 768->1536 (2 tiles/block),
// single 16KB x-buffer (LDS 40960->24576) -> 6 blocks/CU (was 3, LDS-capped).
// R13's -3.6us from the V-scatter vectorization proved proj is a live
// component of the residual; this attacks its barrier-convoy with TLP.

// ---------------------------------------------------------------------------
// Kernel 1: W [k][n] fp32 -> Wt bf16 [p][n][k]
// ---------------------------------------------------------------------------
__global__ __launch_bounds__(256) void prep_wt(const float* __restrict__ Wq,
                                               const float* __restrict__ Wk,
                                               const float* __restrict__ Wv,
                                               bf16* __restrict__ Wt) {
  const int idx = blockIdx.x * 256 + threadIdx.x;
  const int p = idx >> 16;
  const int rem = idx & 65535;  // k*256 + n
  const int k = rem >> 8, n = rem & 255;
  const float* W = (p == 0) ? Wq : ((p == 1) ? Wk : Wv);
  Wt[p * 65536 + n * 256 + k] = (bf16)W[rem];
}

// ---------------------------------------------------------------------------
// Kernel 2: weight-stationary QKV projection (R14):
//   grid 1536 = 6 fams x 256 rgroups; block = 64 rows (2 x 32-row tiles);
//   SINGLE 16KB x-buffer (reg-staged prefetch preserved: next tile loads
//   into xr during tile-t MFMA, written to LDS only after the barrier that
//   fences all tile-t reads) -> LDS 24576 -> 6 blocks/CU (VGPR 84 allows 6
//   waves/SIMD). V-scatter bf16x4 vectorization kept from R13.
// ---------------------------------------------------------------------------
__global__ __launch_bounds__(256, 4) void proj_qkv(const float* __restrict__ x,
                                                   const float* __restrict__ bq,
                                                   const float* __restrict__ bk,
                                                   const float* __restrict__ bv,
                                                   char* __restrict__ ws0) {
  __shared__ __align__(16) char smem[24576];  // 16KB x-tile + 8KB out
  const bf16* Wt = (const bf16*)(ws0 + WT_OFF);
  bf16* Qo = (bf16*)(ws0 + Q_OFF);
  bf16* Ko = (bf16*)(ws0 + K_OFF);
  bf16* Vc = (bf16*)(ws0 + V_OFF);
  const int t = threadIdx.x;
  const int lane = t & 63, w = t >> 6, l16 = lane & 15, quad = lane >> 4;
  const int fam = blockIdx.x % 6;    // consecutive blocks: same rows, all 6
  const int rgroup = blockIdx.x / 6; // 0..255: 64-row groups, L2-hot x
  const int p = fam >> 1, ch = fam & 1;
  const float* bias = (p == 0) ? bq : ((p == 1) ? bk : bv);
  const float sc = (p == 0) ? 0.09016844005556021f : 1.0f;  // log2e/16

  // ---- persistent B-frags: wave owns 32 cols (2 x 16), full K=256 ----
  const int nl = w * 32 + l16;  // block-local col, nt adds +16
  bf16x8 bfr[2][8];
#pragma unroll
  for (int nt = 0; nt < 2; ++nt)
#pragma unroll
    for (int kt = 0; kt < 8; ++kt)
      bfr[nt][kt] = *(const bf16x8*)&Wt[p * 65536 + (ch * 128 + nl + nt * 16) * 256 +
                                        kt * 32 + quad * 8];
  float bias2[2];
#pragma unroll
  for (int nt = 0; nt < 2; ++nt) bias2[nt] = bias[ch * 128 + nl + nt * 16];

  const int row0 = rgroup * 64;  // global first row of this block
  char* outL = smem + 16384;

  float4 xr[4][2];  // in-flight x tile (32 rows x 256 fp32 / 256 thr = 128B/thr)
#define STAGE_LOAD(tile)                                                        \
  {                                                                             \
    const float* xp = x + (row0 + (tile) * 32) * 256;                           \
    _Pragma("unroll") for (int i = 0; i < 4; ++i) {                             \
      const int u2 = i * 256 + t, row = u2 >> 5, col8 = (u2 & 31) * 8;          \
      xr[i][0] = *(const float4*)&xp[row * 256 + col8];                         \
      xr[i][1] = *(const float4*)&xp[row * 256 + col8 + 4];                     \
    }                                                                           \
  }
#define STAGE_WRITE()                                                           \
  {                                                                             \
    _Pragma("unroll") for (int i = 0; i < 4; ++i) {                             \
      const int u2 = i * 256 + t, row = u2 >> 5, col8 = (u2 & 31) * 8;          \
      const float* f0 = (const float*)&xr[i][0];                                \
      const float* f1 = (const float*)&xr[i][1];                                \
      bf16x8 h;                                                                 \
      _Pragma("unroll") for (int j = 0; j < 4; ++j) {                           \
        h[j] = (bf16)f0[j];                                                     \
        h[4 + j] = (bf16)f1[j];                                                 \
      }                                                                         \
      *(bf16x8*)&smem[row * 512 + ((col8 * 2) ^ ((row & 7) << 4))] = h;         \
    }                                                                           \
  }

  STAGE_LOAD(0);
  STAGE_WRITE();
  __syncthreads();

  for (int tt = 0; tt < 2; ++tt) {
    if (tt < 1) STAGE_LOAD(1);  // into regs; LDS write deferred past barrier

    // ---- 32 MFMAs from swizzled LDS A-frags + register B-frags ----
    f32x4 acc[2][2];
#pragma unroll
    for (int rs = 0; rs < 2; ++rs)
#pragma unroll
      for (int nt = 0; nt < 2; ++nt) acc[rs][nt] = f32x4{0.f, 0.f, 0.f, 0.f};
#pragma unroll
    for (int rs = 0; rs < 2; ++rs) {
      const int row = rs * 16 + l16;
#pragma unroll
      for (int kt = 0; kt < 8; ++kt) {
        const bf16x8 a = *(const bf16x8*)(smem + row * 512 +
                                          ((kt * 64 + quad * 16) ^ ((l16 & 7) << 4)));
        acc[rs][0] = MFMA_X32(a, bfr[0][kt], acc[rs][0]);
        acc[rs][1] = MFMA_X32(a, bfr[1][kt], acc[rs][1]);
      }
    }
    __syncthreads();  // all x-tile reads + prev tile's outL reads complete

    // ---- scatter acc into outL in the flash permutation ----
#pragma unroll
    for (int rs = 0; rs < 2; ++rs)
#pragma unroll
      for (int nt = 0; nt < 2; ++nt) {
        const int nn = nl + nt * 16;  // block-local col 0..127
        if (p == 2) {
          // Vc: pos(r) = (nn>>4)*512 + quad*128 + (nn&15)*8 + rs*4 + r
          // -> the 4 r-values are CONTIGUOUS: one aligned bf16x4 write.
          bf16x4v v4;
#pragma unroll
          for (int r = 0; r < 4; ++r)
            v4[r] = (bf16)(acc[rs][nt][r] + bias2[nt]);
          const int pos0 = (nn >> 4) * 512 + quad * 128 + (nn & 15) * 8 + rs * 4;
          *(bf16x4v*)(outL + pos0 * 2) = v4;
        } else {
#pragma unroll
          for (int r = 0; r < 4; ++r) {
            const int sl = rs * 16 + quad * 4 + r;  // C/D: row = quad*4+r
            const bf16 hv = (bf16)((acc[rs][nt][r] + bias2[nt]) * sc);
            int pos;
            if (p == 0)
              pos = sl * 128 + nn;
            else
              pos = (sl >> 4) * 2048 + (nn >> 5) * 512 + ((nn >> 3) & 3) * 128 +
                    (sl & 15) * 8 + (nn & 7);
            *(bf16*)(outL + pos * 2) = hv;
          }
        }
      }
    if (tt < 1) STAGE_WRITE();  // safe: tile-0 reads fenced by barrier above
    __syncthreads();  // scatter + next x-tile visible to all waves

    // ---- coalesced 32B/thread write of the 8KB out tile ----
    const int rowg = row0 + tt * 32;
    if (p == 0) {
      const int row = t >> 3, cb = (t & 7) * 32;
      const float4 v0 = *(const float4*)(outL + row * 256 + cb);
      const float4 v1 = *(const float4*)(outL + row * 256 + cb + 16);
      char* dst = (char*)Qo + (rowg + row) * 512 + ch * 256 + cb;
      *(float4*)dst = v0;
      *(float4*)(dst + 16) = v1;
    } else if (p == 1) {
      const int b2 = rowg >> 11, s0 = rowg & 2047;
      char* dst = (char*)Ko + b2 * 1048576 + ((s0 >> 4) + (t >> 7)) * 8192 +
                  ch * 4096 + (t & 127) * 32;
      const float4 v0 = *(const float4*)(outL + t * 32);
      const float4 v1 = *(const float4*)(outL + t * 32 + 16);
      *(float4*)dst = v0;
      *(float4*)(dst + 16) = v1;
    } else {
      const int b2 = rowg >> 11, s0 = rowg & 2047;
      char* dst = (char*)Vc + b2 * 1048576 + (s0 >> 5) * 16384 + ch * 8192 + t * 32;
      const float4 v0 = *(const float4*)(outL + t * 32);
      const float4 v1 = *(const float4*)(outL + t * 32 + 16);
      *(float4*)dst = v0;
      *(float4*)(dst + 16) = v1;
    }
  }
#undef STAGE_LOAD
#undef STAGE_WRITE
}

// ---------------------------------------------------------------------------
// Kernel 3: flash attention — EXACT R8 (counter-checksummed in R13).
// ---------------------------------------------------------------------------
#define SLOT_SZ 16640  // merge slot: 16 rows * 260 floats (conflict-free)

__global__ __launch_bounds__(512, 2) void flash_attn(const char* __restrict__ ws0,
                                                     float* __restrict__ out) {
  __shared__ __align__(1024) char smem[135168];  // K 2x32KB + V 64KB + scratch
  const bf16* Qp = (const bf16*)(ws0 + Q_OFF);
  const int t = threadIdx.x;
  const int lane = t & 63, w = t >> 6;
  const int l16 = lane & 15, quad = lane >> 4;
  const int qs = w & 1, kq = w >> 1;
  const int b = blockIdx.x & 7;  // batch == XCD round-robin: K/V L2-resident
  const int qt = blockIdx.x >> 3;
  const int qrow0 = b * 2048 + qt * 64 + qs * 32;

  bf16x8 qf[2][8];
#pragma unroll
  for (int qsub = 0; qsub < 2; ++qsub)
#pragma unroll
    for (int kt = 0; kt < 8; ++kt)
      qf[qsub][kt] =
          *(const bf16x8*)&Qp[(qrow0 + qsub * 16 + l16) * 256 + kt * 32 + quad * 8];

  f32x4 o[2][16];
#pragma unroll
  for (int qsub = 0; qsub < 2; ++qsub)
#pragma unroll
    for (int dt = 0; dt < 16; ++dt) o[qsub][dt] = f32x4{0.f, 0.f, 0.f, 0.f};
  float m_[2] = {-1e30f, -1e30f}, l_[2] = {0.f, 0.f};  // l_ is PER-LANE partial

  // K staging: 32 units/step (8 waves x 4), 1KB each; 16-key chunk = 8KB/kq.
  unsigned goffK[4], loffK[4];
#pragma unroll
  for (int i = 0; i < 4; ++i) {
    const int u = w * 4 + i;
    const int kq2 = u >> 3, e = u & 7;
    goffK[i] = (unsigned)K_OFF + b * 1048576u + kq2 * 262144u + e * 1024u + lane * 16u;
    loffK[i] = kq2 * 8192u + e * 1024u;
  }
  // V staging: 64 units/pair (8 waves x 8), 1KB each; 32-key block = 16KB/kq.
  unsigned goffV[8], loffV[8];
#pragma unroll
  for (int i = 0; i < 8; ++i) {
    const int u = w * 8 + i;
    const int kqv = u >> 4, e = u & 15;
    goffV[i] = (unsigned)V_OFF + b * 1048576u + kqv * 262144u + e * 1024u + lane * 16u;
    loffV[i] = 65536u + kqv * 16384u + e * 1024u;
  }

#define STAGE_K(S)                                                             \
  {                                                                            \
    _Pragma("unroll") for (int i = 0; i < 4; ++i)                              \
        gll16(ws0 + goffK[i] + (unsigned)(S) * 8192u,                          \
              smem + (unsigned)(((S) & 1) * 32768) + loffK[i]);                \
  }
#define STAGE_V(P)                                                             \
  {                                                                            \
    _Pragma("unroll") for (int i = 0; i < 8; ++i)                              \
        gll16(ws0 + goffV[i] + (unsigned)(P) * 16384u, smem + loffV[i]);       \
  }
#define QK_STEP(CURK, KC)                                                      \
  {                                                                            \
    const char* kb = smem + (CURK) + kq * 8192 + lane * 16;                    \
    __builtin_amdgcn_s_setprio(1);                                             \
    _Pragma("unroll") for (int kt = 0; kt < 8; ++kt) {                         \
      const bf16x8 kf = *(const bf16x8*)(kb + kt * 1024);                      \
      sfr[0][KC] = MFMA_X32(kf, qf[0][kt], sfr[0][KC]);                        \
      sfr[1][KC] = MFMA_X32(kf, qf[1][kt], sfr[1][KC]);                        \
    }                                                                          \
    __builtin_amdgcn_s_setprio(0);                                             \
  }

  STAGE_K(0);  // prologue

  for (int p = 0; p < 16; ++p) {
    f32x4 sfr[2][2];
#pragma unroll
    for (int qsub = 0; qsub < 2; ++qsub)
#pragma unroll
      for (int kc = 0; kc < 2; ++kc) sfr[qsub][kc] = f32x4{0.f, 0.f, 0.f, 0.f};

    // ---- step 2p: K(2p) resident; stage K(2p+1) + V(p) ----
    __syncthreads();
    STAGE_K(2 * p + 1);
    STAGE_V(p);
    QK_STEP((unsigned)((2 * p) & 1) * 32768u, 0);

    // ---- step 2p+1: K(2p+1) + V(p) resident; stage K(2p+2) ----
    __syncthreads();
    if (p < 15) STAGE_K(2 * p + 2);
    QK_STEP((unsigned)((2 * p + 1) & 1) * 32768u, 1);

    // ---- online softmax over 32 keys (log2; q=l16, key=kc*16+quad*4+r) ----
    // Common path: NO cross-lane ops.
    bf16x8 pa[2];
#pragma unroll
    for (int qsub = 0; qsub < 2; ++qsub) {
      const f32x4 sA = sfr[qsub][0], sB = sfr[qsub][1];
      const float cml = fmaxf(fmaxf(fmaxf(sA[0], sA[1]), fmaxf(sA[2], sA[3])),
                              fmaxf(fmaxf(sB[0], sB[1]), fmaxf(sB[2], sB[3])));
      const float mold = m_[qsub];
      if (__builtin_expect(__any(cml > mold + 6.0f), 0)) {  // defer-max (T13)
        float cm = fmaxf(cml, __shfl_xor(cml, 16));
        cm = fmaxf(cm, __shfl_xor(cm, 32));  // row max (quad-replicated)
        const float Mnew = fmaxf(mold, cm);
        const float al = fast_exp2(mold - Mnew);  // row-uniform across quads
        m_[qsub] = Mnew;
        l_[qsub] *= al;  // per-lane partial scales identically
        float ar[4];
#pragma unroll
        for (int r = 0; r < 4; ++r)
          ar[r] = __shfl(al, (quad << 4) + (quad << 2) + r);
#pragma unroll
        for (int dt = 0; dt < 16; ++dt)
#pragma unroll
          for (int r = 0; r < 4; ++r) o[qsub][dt][r] *= ar[r];
      }
      const float Mref = m_[qsub];
      float ps = 0.f;
#pragma unroll
      for (int r = 0; r < 4; ++r) {
        const bf16 p0 = (bf16)fast_exp2(sA[r] - Mref);
        const bf16 p1 = (bf16)fast_exp2(sB[r] - Mref);
        pa[qsub][r] = p0;
        pa[qsub][4 + r] = p1;
        ps += (float)p0 + (float)p1;  // sum ROUNDED p for O/l consistency
      }
      l_[qsub] += ps;  // per-lane; quad-reduced once after the loop
    }

    // ---- O += P · V: 32-key x32 MFMAs; V b128 LINEAR from single buffer ----
    const char* vb = smem + 65536 + kq * 16384 + lane * 16;
    __builtin_amdgcn_s_setprio(1);
#pragma unroll
    for (int dt = 0; dt < 16; ++dt) {
      const bf16x8 vf = *(const bf16x8*)(vb + dt * 1024);
      o[0][dt] = MFMA_X32(pa[0], vf, o[0][dt]);
      o[1][dt] = MFMA_X32(pa[1], vf, o[1][dt]);
    }
    __builtin_amdgcn_s_setprio(0);
  }
#undef STAGE_K
#undef STAGE_V
#undef QK_STEP

  // ---- deferred l quad-reduction: 2 shuffles per qsub, ONCE ----
#pragma unroll
  for (int qsub = 0; qsub < 2; ++qsub) {
    l_[qsub] += __shfl_xor(l_[qsub], 16);
    l_[qsub] += __shfl_xor(l_[qsub], 32);  // row total, quad-replicated
  }

  // ---- merge 4 kq partials (slots overlay staging buffers; reads done) ----
  float* mlf = (float*)(smem + 133120);  // beyond merge slots: no overlap
  if (quad == 0) {
#pragma unroll
    for (int qsub = 0; qsub < 2; ++qsub) {
      const int base = ((kq * 2 + qs) * 2 + qsub) * 32;
      mlf[base + l16] = m_[qsub];
      mlf[base + 16 + l16] = l_[qsub];
    }
  }
  __syncthreads();
#pragma unroll
  for (int qsub = 0; qsub < 2; ++qsub) {
    float M = -1e30f, mk[4], lk[4];
#pragma unroll
    for (int k2 = 0; k2 < 4; ++k2) {
      const int base = ((k2 * 2 + qs) * 2 + qsub) * 32;
      mk[k2] = mlf[base + l16];
      lk[k2] = mlf[base + 16 + l16];
      M = fmaxf(M, mk[k2]);
    }
    float L = 0.f;
#pragma unroll
    for (int k2 = 0; k2 < 4; ++k2) L += lk[k2] * fast_exp2(mk[k2] - M);
    const float sg = fast_exp2(m_[qsub] - M) / L;
    float sr[4];
#pragma unroll
    for (int r = 0; r < 4; ++r) sr[r] = __shfl(sg, (quad << 4) + (quad << 2) + r);
#pragma unroll
    for (int dt = 0; dt < 16; ++dt)
#pragma unroll
      for (int r = 0; r < 4; ++r) o[qsub][dt][r] *= sr[r];
  }
  if (kq >= 2) {
#pragma unroll
    for (int qsub = 0; qsub < 2; ++qsub) {
      float* sb = (float*)(smem + ((kq - 2) * 4 + qs * 2 + qsub) * SLOT_SZ);
#pragma unroll
      for (int dt = 0; dt < 16; ++dt)
#pragma unroll
        for (int r = 0; r < 4; ++r)
          sb[(quad * 4 + r) * 260 + dt * 16 + l16] = o[qsub][dt][r];
    }
  }
  __syncthreads();
  if (kq < 2) {
#pragma unroll
    for (int qsub = 0; qsub < 2; ++qsub) {
      const float* sb = (const float*)(smem + (kq * 4 + qs * 2 + qsub) * SLOT_SZ);
#pragma unroll
      for (int dt = 0; dt < 16; ++dt)
#pragma unroll
        for (int r = 0; r < 4; ++r)
          o[qsub][dt][r] += sb[(quad * 4 + r) * 260 + dt * 16 + l16];
    }
  }
  __syncthreads();
  if (kq == 1) {
#pragma unroll
    for (int qsub = 0; qsub < 2; ++qsub) {
      float* sb = (float*)(smem + (qs * 2 + qsub) * SLOT_SZ);
#pragma unroll
      for (int dt = 0; dt < 16; ++dt)
#pragma unroll
        for (int r = 0; r < 4; ++r)
          sb[(quad * 4 + r) * 260 + dt * 16 + l16] = o[qsub][dt][r];
    }
  }
  __syncthreads();
  if (kq == 0) {
#pragma unroll
    for (int qsub = 0; qsub < 2; ++qsub) {
      const float* sb = (const float*)(smem + (qs * 2 + qsub) * SLOT_SZ);
#pragma unroll
      for (int dt = 0; dt < 16; ++dt)
#pragma unroll
        for (int r = 0; r < 4; ++r) {
          const float v = o[qsub][dt][r] + sb[(quad * 4 + r) * 260 + dt * 16 + l16];
          out[(qrow0 + qsub * 16 + quad * 4 + r) * 256 + dt * 16 + l16] = v;
        }
    }
  }
}

extern "C" void kernel_launch(void* const* d_in, const int* in_sizes, int n_in,
                              void* d_out, int out_size, void* d_ws,
                              size_t ws_size, hipStream_t stream) {
  const float* x = (const float*)d_in[0];
  const float* Wq = (const float*)d_in[1];
  const float* bq = (const float*)d_in[2];
  const float* Wk = (const float*)d_in[3];
  const float* bk = (const float*)d_in[4];
  const float* Wv = (const float*)d_in[5];
  const float* bv = (const float*)d_in[6];
  float* out = (float*)d_out;
  char* ws = (char*)d_ws;

  prep_wt<<<768, 256, 0, stream>>>(Wq, Wk, Wv, (bf16*)(ws + WT_OFF));
  proj_qkv<<<1536, 256, 0, stream>>>(x, bq, bk, bv, ws);
  flash_attn<<<256, 512, 0, stream>>>(ws, out);
}

// Round 15
// 153.948 us; speedup vs baseline: 1.0741x; 1.0741x over previous
//
#include <hip/hip_runtime.h>

typedef __bf16 bf16;
typedef __bf16 bf16x4v __attribute__((ext_vector_type(4)));
typedef __bf16 bf16x8 __attribute__((ext_vector_type(8)));
typedef float f32x4 __attribute__((ext_vector_type(4)));
typedef short s16x4 __attribute__((ext_vector_type(4)));

#define MFMA_X32(A, B, C) __builtin_amdgcn_mfma_f32_16x16x32_bf16(A, B, C, 0, 0, 0)

static __device__ __forceinline__ float fast_exp2(float x) {
  float r;
  asm volatile("v_exp_f32 %0, %1\n\ts_nop 0" : "=v"(r) : "v"(x));
  return r;
}

static __device__ __forceinline__ void gll16(const void* g, void* l) {
  __builtin_amdgcn_global_load_lds(
      (const __attribute__((address_space(1))) void*)g,
      (__attribute__((address_space(3))) void*)l, 16, 0, 0);
}

// ---- workspace byte offsets (R8/R13 layout) ----
#define WT_OFF 0              // Wt bf16 [3][256 n][256 k]          (384 KB)
#define Q_OFF 393216          // Q' bf16 [16384][256] (pre-scaled)   (8 MB)
#define K_OFF 8781824         // Kc bf16 chunk-permuted (see below)  (8 MB)
#define V_OFF 17170432        // Vc bf16 32-key-permuted             (8 MB)
// Kc: per (b, 16-key chunk) 8KB block; element (key s, dim n) at
//   (n>>5)*512 + ((n>>3)&3)*128 + (s&15)*8 + (n&7)
//   => flash K-frag ds_read_b128 addr = base + kt*1024 + lane*16 (LINEAR).
// Vc: per (b, 32-key chunk) 16KB block; element (key s, dim n) at
//   byte = (n>>4)*1024 + ((s>>2)&3)*256 + (n&15)*16 + ((s>>4)*4 + (s&3))*2
//   => flash PV B-frag (16x16x32) addr = base + dt*1024 + lane*16 (LINEAR).
// R15 = exact R13 (best measured: 154.9us; R14's proj restructure cost 12us
// and is reverted) + prep_wt rewritten as an LDS tile transpose (the old
// version's Wt store was fully uncoalesced: 64 lanes x 512B-strided sectors).

// ---------------------------------------------------------------------------
// Kernel 1 (R15): W [k][n] fp32 -> Wt bf16 [p][n][k] via LDS 64x64 transpose.
// 48 blocks = 3 p x 16 tiles; coalesced float4 reads, padded LDS tile,
// 32B-contiguous coalesced writes. Conversion bit-identical to the old path.
// ---------------------------------------------------------------------------
__global__ __launch_bounds__(256) void prep_wt(const float* __restrict__ Wq,
                                               const float* __restrict__ Wk,
                                               const float* __restrict__ Wv,
                                               bf16* __restrict__ Wt) {
  __shared__ bf16 tile[64][72];  // +8 pad: transposed reads spread banks
  const int t = threadIdx.x;
  const int p = blockIdx.x / 16, tid = blockIdx.x % 16;
  const int k0 = (tid >> 2) * 64, n0 = (tid & 3) * 64;  // tile origin in W
  const float* W = (p == 0) ? Wq : ((p == 1) ? Wk : Wv);

  // load: thread -> row r = t>>2 (0..63), 16 consecutive cols at (t&3)*16
  {
    const int r = t >> 2, c = (t & 3) * 16;
    const float* src = &W[(k0 + r) * 256 + n0 + c];
#pragma unroll
    for (int j = 0; j < 4; ++j) {
      const float4 v = *(const float4*)(src + j * 4);
      tile[r][c + j * 4 + 0] = (bf16)v.x;
      tile[r][c + j * 4 + 1] = (bf16)v.y;
      tile[r][c + j * 4 + 2] = (bf16)v.z;
      tile[r][c + j * 4 + 3] = (bf16)v.w;
    }
  }
  __syncthreads();
  // store: thread -> out-row n = t>>2, 16 consecutive k at (t&3)*16
  {
    const int n = t >> 2, kc = (t & 3) * 16;
    bf16* dst = &Wt[p * 65536 + (n0 + n) * 256 + k0 + kc];
#pragma unroll
    for (int j = 0; j < 16; ++j) dst[j] = tile[kc + j][n];
  }
}

// ---------------------------------------------------------------------------
// Kernel 2: weight-stationary QKV projection — EXACT R13 (grid 768, dbuf,
// V-scatter bf16x4 vectorized).
// ---------------------------------------------------------------------------
__global__ __launch_bounds__(256, 3) void proj_qkv(const float* __restrict__ x,
                                                   const float* __restrict__ bq,
                                                   const float* __restrict__ bk,
                                                   const float* __restrict__ bv,
                                                   char* __restrict__ ws0) {
  __shared__ __align__(16) char smem[40960];  // 2 x 16KB swizzled x-tile + 8KB out
  const bf16* Wt = (const bf16*)(ws0 + WT_OFF);
  bf16* Qo = (bf16*)(ws0 + Q_OFF);
  bf16* Ko = (bf16*)(ws0 + K_OFF);
  bf16* Vc = (bf16*)(ws0 + V_OFF);
  const int t = threadIdx.x;
  const int lane = t & 63, w = t >> 6, l16 = lane & 15, quad = lane >> 4;
  const int fam = blockIdx.x % 6;    // consecutive blocks: same rows, all 6
  const int rgroup = blockIdx.x / 6; // families -> x tiles L2/L3-hot across XCDs
  const int p = fam >> 1, ch = fam & 1;
  const float* bias = (p == 0) ? bq : ((p == 1) ? bk : bv);
  const float sc = (p == 0) ? 0.09016844005556021f : 1.0f;  // log2e/16

  // ---- persistent B-frags: wave owns 32 cols (2 x 16), full K=256 ----
  const int nl = w * 32 + l16;  // block-local col, nt adds +16
  bf16x8 bfr[2][8];
#pragma unroll
  for (int nt = 0; nt < 2; ++nt)
#pragma unroll
    for (int kt = 0; kt < 8; ++kt)
      bfr[nt][kt] = *(const bf16x8*)&Wt[p * 65536 + (ch * 128 + nl + nt * 16) * 256 +
                                        kt * 32 + quad * 8];
  float bias2[2];
#pragma unroll
  for (int nt = 0; nt < 2; ++nt) bias2[nt] = bias[ch * 128 + nl + nt * 16];

  const int row0 = rgroup * 128;  // global first row of this block
  char* outL = smem + 32768;

  float4 xr[4][2];  // in-flight x tile (32 rows x 256 fp32 / 256 thr = 128B/thr)
#define STAGE_LOAD(tile)                                                        \
  {                                                                             \
    const float* xp = x + (row0 + (tile) * 32) * 256;                           \
    _Pragma("unroll") for (int i = 0; i < 4; ++i) {                             \
      const int u2 = i * 256 + t, row = u2 >> 5, col8 = (u2 & 31) * 8;          \
      xr[i][0] = *(const float4*)&xp[row * 256 + col8];                         \
      xr[i][1] = *(const float4*)&xp[row * 256 + col8 + 4];                     \
    }                                                                           \
  }
#define STAGE_WRITE(buf)                                                        \
  {                                                                             \
    _Pragma("unroll") for (int i = 0; i < 4; ++i) {                             \
      const int u2 = i * 256 + t, row = u2 >> 5, col8 = (u2 & 31) * 8;          \
      const float* f0 = (const float*)&xr[i][0];                                \
      const float* f1 = (const float*)&xr[i][1];                                \
      bf16x8 h;                                                                 \
      _Pragma("unroll") for (int j = 0; j < 4; ++j) {                           \
        h[j] = (bf16)f0[j];                                                     \
        h[4 + j] = (bf16)f1[j];                                                 \
      }                                                                         \
      *(bf16x8*)&smem[(buf) * 16384 + row * 512 +                               \
                      ((col8 * 2) ^ ((row & 7) << 4))] = h;                     \
    }                                                                           \
  }

  STAGE_LOAD(0);
  STAGE_WRITE(0);
  __syncthreads();

  int cur = 0;
  for (int tt = 0; tt < 4; ++tt) {
    if (tt < 3) STAGE_LOAD(tt + 1);  // issue early; consumed after next barrier

    // ---- 32 MFMAs from swizzled LDS A-frags + register B-frags ----
    f32x4 acc[2][2];
#pragma unroll
    for (int rs = 0; rs < 2; ++rs)
#pragma unroll
      for (int nt = 0; nt < 2; ++nt) acc[rs][nt] = f32x4{0.f, 0.f, 0.f, 0.f};
    const char* xb = smem + cur * 16384;
#pragma unroll
    for (int rs = 0; rs < 2; ++rs) {
      const int row = rs * 16 + l16;
#pragma unroll
      for (int kt = 0; kt < 8; ++kt) {
        const bf16x8 a = *(const bf16x8*)(xb + row * 512 +
                                          ((kt * 64 + quad * 16) ^ ((l16 & 7) << 4)));
        acc[rs][0] = MFMA_X32(a, bfr[0][kt], acc[rs][0]);
        acc[rs][1] = MFMA_X32(a, bfr[1][kt], acc[rs][1]);
      }
    }
    __syncthreads();  // prev tile's coop-write reads of outL complete

    // ---- scatter acc into outL in the flash permutation ----
#pragma unroll
    for (int rs = 0; rs < 2; ++rs)
#pragma unroll
      for (int nt = 0; nt < 2; ++nt) {
        const int nn = nl + nt * 16;  // block-local col 0..127
        if (p == 2) {
          // Vc: pos(r) = (nn>>4)*512 + quad*128 + (nn&15)*8 + rs*4 + r
          // -> the 4 r-values are CONTIGUOUS: one aligned bf16x4 write.
          bf16x4v v4;
#pragma unroll
          for (int r = 0; r < 4; ++r)
            v4[r] = (bf16)(acc[rs][nt][r] + bias2[nt]);
          const int pos0 = (nn >> 4) * 512 + quad * 128 + (nn & 15) * 8 + rs * 4;
          *(bf16x4v*)(outL + pos0 * 2) = v4;
        } else {
#pragma unroll
          for (int r = 0; r < 4; ++r) {
            const int sl = rs * 16 + quad * 4 + r;  // C/D: row = quad*4+r
            const bf16 hv = (bf16)((acc[rs][nt][r] + bias2[nt]) * sc);
            int pos;
            if (p == 0)
              pos = sl * 128 + nn;
            else
              pos = (sl >> 4) * 2048 + (nn >> 5) * 512 + ((nn >> 3) & 3) * 128 +
                    (sl & 15) * 8 + (nn & 7);
            *(bf16*)(outL + pos * 2) = hv;
          }
        }
      }
    if (tt < 3) STAGE_WRITE(cur ^ 1);
    __syncthreads();  // scatter + next x-tile visible to all waves

    // ---- coalesced 32B/thread write of the 8KB out tile ----
    const int rowg = row0 + tt * 32;
    if (p == 0) {
      const int row = t >> 3, cb = (t & 7) * 32;
      const float4 v0 = *(const float4*)(outL + row * 256 + cb);
      const float4 v1 = *(const float4*)(outL + row * 256 + cb + 16);
      char* dst = (char*)Qo + (rowg + row) * 512 + ch * 256 + cb;
      *(float4*)dst = v0;
      *(float4*)(dst + 16) = v1;
    } else if (p == 1) {
      const int b2 = rowg >> 11, s0 = rowg & 2047;
      char* dst = (char*)Ko + b2 * 1048576 + ((s0 >> 4) + (t >> 7)) * 8192 +
                  ch * 4096 + (t & 127) * 32;
      const float4 v0 = *(const float4*)(outL + t * 32);
      const float4 v1 = *(const float4*)(outL + t * 32 + 16);
      *(float4*)dst = v0;
      *(float4*)(dst + 16) = v1;
    } else {
      const int b2 = rowg >> 11, s0 = rowg & 2047;
      char* dst = (char*)Vc + b2 * 1048576 + (s0 >> 5) * 16384 + ch * 8192 + t * 32;
      const float4 v0 = *(const float4*)(outL + t * 32);
      const float4 v1 = *(const float4*)(outL + t * 32 + 16);
      *(float4*)dst = v0;
      *(float4*)(dst + 16) = v1;
    }
    cur ^= 1;
  }
#undef STAGE_LOAD
#undef STAGE_WRITE
}

// ---------------------------------------------------------------------------
// Kernel 3: flash attention — EXACT R8/R13 (counter-checksummed twice).
// ---------------------------------------------------------------------------
#define SLOT_SZ 16640  // merge slot: 16 rows * 260 floats (conflict-free)

__global__ __launch_bounds__(512, 2) void flash_attn(const char* __restrict__ ws0,
                                                     float* __restrict__ out) {
  __shared__ __align__(1024) char smem[135168];  // K 2x32KB + V 64KB + scratch
  const bf16* Qp = (const bf16*)(ws0 + Q_OFF);
  const int t = threadIdx.x;
  const int lane = t & 63, w = t >> 6;
  const int l16 = lane & 15, quad = lane >> 4;
  const int qs = w & 1, kq = w >> 1;
  const int b = blockIdx.x & 7;  // batch == XCD round-robin: K/V L2-resident
  const int qt = blockIdx.x >> 3;
  const int qrow0 = b * 2048 + qt * 64 + qs * 32;

  bf16x8 qf[2][8];
#pragma unroll
  for (int qsub = 0; qsub < 2; ++qsub)
#pragma unroll
    for (int kt = 0; kt < 8; ++kt)
      qf[qsub][kt] =
          *(const bf16x8*)&Qp[(qrow0 + qsub * 16 + l16) * 256 + kt * 32 + quad * 8];

  f32x4 o[2][16];
#pragma unroll
  for (int qsub = 0; qsub < 2; ++qsub)
#pragma unroll
    for (int dt = 0; dt < 16; ++dt) o[qsub][dt] = f32x4{0.f, 0.f, 0.f, 0.f};
  float m_[2] = {-1e30f, -1e30f}, l_[2] = {0.f, 0.f};  // l_ is PER-LANE partial

  // K staging: 32 units/step (8 waves x 4), 1KB each; 16-key chunk = 8KB/kq.
  unsigned goffK[4], loffK[4];
#pragma unroll
  for (int i = 0; i < 4; ++i) {
    const int u = w * 4 + i;
    const int kq2 = u >> 3, e = u & 7;
    goffK[i] = (unsigned)K_OFF + b * 1048576u + kq2 * 262144u + e * 1024u + lane * 16u;
    loffK[i] = kq2 * 8192u + e * 1024u;
  }
  // V staging: 64 units/pair (8 waves x 8), 1KB each; 32-key block = 16KB/kq.
  unsigned goffV[8], loffV[8];
#pragma unroll
  for (int i = 0; i < 8; ++i) {
    const int u = w * 8 + i;
    const int kqv = u >> 4, e = u & 15;
    goffV[i] = (unsigned)V_OFF + b * 1048576u + kqv * 262144u + e * 1024u + lane * 16u;
    loffV[i] = 65536u + kqv * 16384u + e * 1024u;
  }

#define STAGE_K(S)                                                             \
  {                                                                            \
    _Pragma("unroll") for (int i = 0; i < 4; ++i)                              \
        gll16(ws0 + goffK[i] + (unsigned)(S) * 8192u,                          \
              smem + (unsigned)(((S) & 1) * 32768) + loffK[i]);                \
  }
#define STAGE_V(P)                                                             \
  {                                                                            \
    _Pragma("unroll") for (int i = 0; i < 8; ++i)                              \
        gll16(ws0 + goffV[i] + (unsigned)(P) * 16384u, smem + loffV[i]);       \
  }
#define QK_STEP(CURK, KC)                                                      \
  {                                                                            \
    const char* kb = smem + (CURK) + kq * 8192 + lane * 16;                    \
    __builtin_amdgcn_s_setprio(1);                                             \
    _Pragma("unroll") for (int kt = 0; kt < 8; ++kt) {                         \
      const bf16x8 kf = *(const bf16x8*)(kb + kt * 1024);                      \
      sfr[0][KC] = MFMA_X32(kf, qf[0][kt], sfr[0][KC]);                        \
      sfr[1][KC] = MFMA_X32(kf, qf[1][kt], sfr[1][KC]);                        \
    }                                                                          \
    __builtin_amdgcn_s_setprio(0);                                             \
  }

  STAGE_K(0);  // prologue

  for (int p = 0; p < 16; ++p) {
    f32x4 sfr[2][2];
#pragma unroll
    for (int qsub = 0; qsub < 2; ++qsub)
#pragma unroll
      for (int kc = 0; kc < 2; ++kc) sfr[qsub][kc] = f32x4{0.f, 0.f, 0.f, 0.f};

    // ---- step 2p: K(2p) resident; stage K(2p+1) + V(p) ----
    __syncthreads();
    STAGE_K(2 * p + 1);
    STAGE_V(p);
    QK_STEP((unsigned)((2 * p) & 1) * 32768u, 0);

    // ---- step 2p+1: K(2p+1) + V(p) resident; stage K(2p+2) ----
    __syncthreads();
    if (p < 15) STAGE_K(2 * p + 2);
    QK_STEP((unsigned)((2 * p + 1) & 1) * 32768u, 1);

    // ---- online softmax over 32 keys (log2; q=l16, key=kc*16+quad*4+r) ----
    // Common path: NO cross-lane ops.
    bf16x8 pa[2];
#pragma unroll
    for (int qsub = 0; qsub < 2; ++qsub) {
      const f32x4 sA = sfr[qsub][0], sB = sfr[qsub][1];
      const float cml = fmaxf(fmaxf(fmaxf(sA[0], sA[1]), fmaxf(sA[2], sA[3])),
                              fmaxf(fmaxf(sB[0], sB[1]), fmaxf(sB[2], sB[3])));
      const float mold = m_[qsub];
      if (__builtin_expect(__any(cml > mold + 6.0f), 0)) {  // defer-max (T13)
        float cm = fmaxf(cml, __shfl_xor(cml, 16));
        cm = fmaxf(cm, __shfl_xor(cm, 32));  // row max (quad-replicated)
        const float Mnew = fmaxf(mold, cm);
        const float al = fast_exp2(mold - Mnew);  // row-uniform across quads
        m_[qsub] = Mnew;
        l_[qsub] *= al;  // per-lane partial scales identically
        float ar[4];
#pragma unroll
        for (int r = 0; r < 4; ++r)
          ar[r] = __shfl(al, (quad << 4) + (quad << 2) + r);
#pragma unroll
        for (int dt = 0; dt < 16; ++dt)
#pragma unroll
          for (int r = 0; r < 4; ++r) o[qsub][dt][r] *= ar[r];
      }
      const float Mref = m_[qsub];
      float ps = 0.f;
#pragma unroll
      for (int r = 0; r < 4; ++r) {
        const bf16 p0 = (bf16)fast_exp2(sA[r] - Mref);
        const bf16 p1 = (bf16)fast_exp2(sB[r] - Mref);
        pa[qsub][r] = p0;
        pa[qsub][4 + r] = p1;
        ps += (float)p0 + (float)p1;  // sum ROUNDED p for O/l consistency
      }
      l_[qsub] += ps;  // per-lane; quad-reduced once after the loop
    }

    // ---- O += P · V: 32-key x32 MFMAs; V b128 LINEAR from single buffer ----
    const char* vb = smem + 65536 + kq * 16384 + lane * 16;
    __builtin_amdgcn_s_setprio(1);
#pragma unroll
    for (int dt = 0; dt < 16; ++dt) {
      const bf16x8 vf = *(const bf16x8*)(vb + dt * 1024);
      o[0][dt] = MFMA_X32(pa[0], vf, o[0][dt]);
      o[1][dt] = MFMA_X32(pa[1], vf, o[1][dt]);
    }
    __builtin_amdgcn_s_setprio(0);
  }
#undef STAGE_K
#undef STAGE_V
#undef QK_STEP

  // ---- deferred l quad-reduction: 2 shuffles per qsub, ONCE ----
#pragma unroll
  for (int qsub = 0; qsub < 2; ++qsub) {
    l_[qsub] += __shfl_xor(l_[qsub], 16);
    l_[qsub] += __shfl_xor(l_[qsub], 32);  // row total, quad-replicated
  }

  // ---- merge 4 kq partials (slots overlay staging buffers; reads done) ----
  float* mlf = (float*)(smem + 133120);  // beyond merge slots: no overlap
  if (quad == 0) {
#pragma unroll
    for (int qsub = 0; qsub < 2; ++qsub) {
      const int base = ((kq * 2 + qs) * 2 + qsub) * 32;
      mlf[base + l16] = m_[qsub];
      mlf[base + 16 + l16] = l_[qsub];
    }
  }
  __syncthreads();
#pragma unroll
  for (int qsub = 0; qsub < 2; ++qsub) {
    float M = -1e30f, mk[4], lk[4];
#pragma unroll
    for (int k2 = 0; k2 < 4; ++k2) {
      const int base = ((k2 * 2 + qs) * 2 + qsub) * 32;
      mk[k2] = mlf[base + l16];
      lk[k2] = mlf[base + 16 + l16];
      M = fmaxf(M, mk[k2]);
    }
    float L = 0.f;
#pragma unroll
    for (int k2 = 0; k2 < 4; ++k2) L += lk[k2] * fast_exp2(mk[k2] - M);
    const float sg = fast_exp2(m_[qsub] - M) / L;
    float sr[4];
#pragma unroll
    for (int r = 0; r < 4; ++r) sr[r] = __shfl(sg, (quad << 4) + (quad << 2) + r);
#pragma unroll
    for (int dt = 0; dt < 16; ++dt)
#pragma unroll
      for (int r = 0; r < 4; ++r) o[qsub][dt][r] *= sr[r];
  }
  if (kq >= 2) {
#pragma unroll
    for (int qsub = 0; qsub < 2; ++qsub) {
      float* sb = (float*)(smem + ((kq - 2) * 4 + qs * 2 + qsub) * SLOT_SZ);
#pragma unroll
      for (int dt = 0; dt < 16; ++dt)
#pragma unroll
        for (int r = 0; r < 4; ++r)
          sb[(quad * 4 + r) * 260 + dt * 16 + l16] = o[qsub][dt][r];
    }
  }
  __syncthreads();
  if (kq < 2) {
#pragma unroll
    for (int qsub = 0; qsub < 2; ++qsub) {
      const float* sb = (const float*)(smem + (kq * 4 + qs * 2 + qsub) * SLOT_SZ);
#pragma unroll
      for (int dt = 0; dt < 16; ++dt)
#pragma unroll
        for (int r = 0; r < 4; ++r)
          o[qsub][dt][r] += sb[(quad * 4 + r) * 260 + dt * 16 + l16];
    }
  }
  __syncthreads();
  if (kq == 1) {
#pragma unroll
    for (int qsub = 0; qsub < 2; ++qsub) {
      float* sb = (float*)(smem + (qs * 2 + qsub) * SLOT_SZ);
#pragma unroll
      for (int dt = 0; dt < 16; ++dt)
#pragma unroll
        for (int r = 0; r < 4; ++r)
          sb[(quad * 4 + r) * 260 + dt * 16 + l16] = o[qsub][dt][r];
    }
  }
  __syncthreads();
  if (kq == 0) {
#pragma unroll
    for (int qsub = 0; qsub < 2; ++qsub) {
      const float* sb = (const float*)(smem + (qs * 2 + qsub) * SLOT_SZ);
#pragma unroll
      for (int dt = 0; dt < 16; ++dt)
#pragma unroll
        for (int r = 0; r < 4; ++r) {
          const float v = o[qsub][dt][r] + sb[(quad * 4 + r) * 260 + dt * 16 + l16];
          out[(qrow0 + qsub * 16 + quad * 4 + r) * 256 + dt * 16 + l16] = v;
        }
    }
  }
}

extern "C" void kernel_launch(void* const* d_in, const int* in_sizes, int n_in,
                              void* d_out, int out_size, void* d_ws,
                              size_t ws_size, hipStream_t stream) {
  const float* x = (const float*)d_in[0];
  const float* Wq = (const float*)d_in[1];
  const float* bq = (const float*)d_in[2];
  const float* Wk = (const float*)d_in[3];
  const float* bk = (const float*)d_in[4];
  const float* Wv = (const float*)d_in[5];
  const float* bv = (const float*)d_in[6];
  float* out = (float*)d_out;
  char* ws = (char*)d_ws;

  prep_wt<<<48, 256, 0, stream>>>(Wq, Wk, Wv, (bf16*)(ws + WT_OFF));
  proj_qkv<<<768, 256, 0, stream>>>(x, bq, bk, bv, ws);
  flash_attn<<<256, 512, 0, stream>>>(ws, out);
}